// Round 2
// baseline (88.095 us; speedup 1.0000x reference)
//
#include <hip/hip_runtime.h>
#include <math.h>

namespace {
constexpr int kB = 2, kC = 3, kOC = 2, kH = 96, kW = 96;
constexpr int kN      = kH * kW;                 // 9216
constexpr int kChunks = kN / 256;                // 36 blocks per (b,oc) plane
constexpr int kBlocks = kB * kOC * kChunks;      // 144
constexpr float kEps   = 1e-5f;
constexpr float kScale = 0.57735026918962576f;   // 1/sqrt(3)
constexpr unsigned kPoison = 0xAAAAAAAAu;        // harness ws poison pattern
// ws u32/f32 word layout:
//   [0]               barrier arrival counter (u32, poison-cleared via CAS)
//   [8 + blk*2 + 0]   per-block partial sum of pre-BN y   (f32)
//   [8 + blk*2 + 1]   per-block partial sum of y^2        (f32)
}

__global__ __launch_bounds__(256) void fused_fea(
    const float* __restrict__ X,    const float* __restrict__ Xhat,
    const float* __restrict__ cw,   const float* __restrict__ cb,
    const float* __restrict__ gamma,const float* __restrict__ beta,
    float* __restrict__ out, unsigned* __restrict__ wsu) {

    const int tid   = threadIdx.x;
    const int blk   = blockIdx.x;
    const int plane = blk / kChunks;          // b*kOC + oc
    const int b     = plane / kOC;
    const int oc    = plane % kOC;
    const int pix   = (blk % kChunks) * 256 + tid;
    const int h = pix / kW, w = pix % kW;

    float* wsf = (float*)wsu;

    __shared__ float sM[9];          // Gram M[cp][c] for batch b
    __shared__ float sMw[4][9];      // per-wave partials
    __shared__ float sW[kC * 9];     // conv_w[oc][ic][3][3]
    __shared__ float sRed[256], sRed2[256];
    __shared__ float sStats[2];      // mean, rstd

    // conv weights for this oc (27 floats) — load early, used after barrier A
    if (tid >= 32 && tid < 32 + kC * 9) sW[tid - 32] = cw[oc * kC * 9 + (tid - 32)];

    // ---- Phase A: M[cp][c] = sum_n Xhat[b,cp,n] * X[b,c,n]  (block-local, redundant)
    const float* qb = X    + (size_t)b * kC * kN;
    const float* kb = Xhat + (size_t)b * kC * kN;
    float m0=0,m1=0,m2=0,m3=0,m4=0,m5=0,m6=0,m7=0,m8=0;
    for (int n = tid; n < kN; n += 256) {
        float q0 = qb[n], q1 = qb[kN + n], q2 = qb[2 * kN + n];
        float k0 = kb[n], k1 = kb[kN + n], k2 = kb[2 * kN + n];
        m0 += k0 * q0; m1 += k0 * q1; m2 += k0 * q2;
        m3 += k1 * q0; m4 += k1 * q1; m5 += k1 * q2;
        m6 += k2 * q0; m7 += k2 * q1; m8 += k2 * q2;
    }
    #pragma unroll
    for (int off = 32; off > 0; off >>= 1) {
        m0 += __shfl_down(m0, off); m1 += __shfl_down(m1, off); m2 += __shfl_down(m2, off);
        m3 += __shfl_down(m3, off); m4 += __shfl_down(m4, off); m5 += __shfl_down(m5, off);
        m6 += __shfl_down(m6, off); m7 += __shfl_down(m7, off); m8 += __shfl_down(m8, off);
    }
    const int wave = tid >> 6;
    if ((tid & 63) == 0) {
        sMw[wave][0]=m0; sMw[wave][1]=m1; sMw[wave][2]=m2;
        sMw[wave][3]=m3; sMw[wave][4]=m4; sMw[wave][5]=m5;
        sMw[wave][6]=m6; sMw[wave][7]=m7; sMw[wave][8]=m8;
    }
    __syncthreads();
    if (tid < 9) sM[tid] = sMw[0][tid] + sMw[1][tid] + sMw[2][tid] + sMw[3][tid];
    __syncthreads();

    // ---- Phase B: agg-on-the-fly + 3x3 conv + bias; y stays in register
    float acc = cb[oc];
    #pragma unroll
    for (int dh = 0; dh < 3; ++dh) {
        const int hh = h + dh - 1;
        if (hh < 0 || hh >= kH) continue;
        #pragma unroll
        for (int dw = 0; dw < 3; ++dw) {
            const int ww = w + dw - 1;
            if (ww < 0 || ww >= kW) continue;
            const int p = hh * kW + ww;
            const float q0 = qb[p];
            const float q1 = qb[kN + p];
            const float q2 = qb[2 * kN + p];
            #pragma unroll
            for (int ic = 0; ic < kC; ++ic) {
                const float a = kScale * (sM[0 * 3 + ic] * q0 +
                                          sM[1 * 3 + ic] * q1 +
                                          sM[2 * 3 + ic] * q2);
                acc += a * sW[ic * 9 + dh * 3 + dw];
            }
        }
    }

    // block reduce sum / sumsq for BN stats
    sRed[tid]  = acc;
    sRed2[tid] = acc * acc;
    __syncthreads();
    for (int s = 128; s > 0; s >>= 1) {
        if (tid < s) { sRed[tid] += sRed[tid + s]; sRed2[tid] += sRed2[tid + s]; }
        __syncthreads();
    }

    // ---- Grid barrier (single use; counter poison-cleared via CAS)
    if (tid == 0) {
        __hip_atomic_store(&wsf[8 + blk * 2 + 0], sRed[0],  __ATOMIC_RELAXED, __HIP_MEMORY_SCOPE_AGENT);
        __hip_atomic_store(&wsf[8 + blk * 2 + 1], sRed2[0], __ATOMIC_RELAXED, __HIP_MEMORY_SCOPE_AGENT);
        unsigned expected = kPoison;
        __hip_atomic_compare_exchange_strong(&wsu[0], &expected, 0u,
            __ATOMIC_RELAXED, __ATOMIC_RELAXED, __HIP_MEMORY_SCOPE_AGENT);
        __hip_atomic_fetch_add(&wsu[0], 1u, __ATOMIC_RELEASE, __HIP_MEMORY_SCOPE_AGENT);
        while (__hip_atomic_load(&wsu[0], __ATOMIC_ACQUIRE, __HIP_MEMORY_SCOPE_AGENT)
               < (unsigned)kBlocks) {
            __builtin_amdgcn_s_sleep(1);
        }
    }
    __syncthreads();

    // ---- Phase C: gather 72 partials for this oc, finalize BN + LeakyReLU
    float ps = 0.f, pq = 0.f;
    if (tid < 2 * kChunks) {
        const int j = (tid < kChunks) ? (oc * kChunks + tid)
                                      : ((kOC + oc) * kChunks + (tid - kChunks));
        ps = __hip_atomic_load(&wsf[8 + j * 2 + 0], __ATOMIC_RELAXED, __HIP_MEMORY_SCOPE_AGENT);
        pq = __hip_atomic_load(&wsf[8 + j * 2 + 1], __ATOMIC_RELAXED, __HIP_MEMORY_SCOPE_AGENT);
    }
    sRed[tid]  = (tid < 2 * kChunks) ? ps : 0.f;
    sRed2[tid] = (tid < 2 * kChunks) ? pq : 0.f;
    __syncthreads();
    for (int s = 128; s > 0; s >>= 1) {
        if (tid < s) { sRed[tid] += sRed[tid + s]; sRed2[tid] += sRed2[tid + s]; }
        __syncthreads();
    }
    if (tid == 0) {
        const float inv  = 1.f / (float)(kB * kN);
        const float mean = sRed[0] * inv;
        const float var  = sRed2[0] * inv - mean * mean;
        sStats[0] = mean;
        sStats[1] = rsqrtf(var + kEps);
    }
    __syncthreads();

    float y = (acc - sStats[0]) * sStats[1] * gamma[oc] + beta[oc];
    out[plane * kN + pix] = (y >= 0.f) ? y : 0.1f * y;
}

extern "C" void kernel_launch(void* const* d_in, const int* in_sizes, int n_in,
                              void* d_out, int out_size, void* d_ws, size_t ws_size,
                              hipStream_t stream) {
    const float* X      = (const float*)d_in[0];  // X_tnext     (2,3,96,96)
    const float* Xhat   = (const float*)d_in[1];  // X_hat_tnext (2,3,96,96)
    const float* conv_w = (const float*)d_in[2];  // (2,3,3,3)
    const float* conv_b = (const float*)d_in[3];  // (2,)
    const float* gamma  = (const float*)d_in[4];  // (2,)
    const float* beta   = (const float*)d_in[5];  // (2,)

    fused_fea<<<kBlocks, 256, 0, stream>>>(X, Xhat, conv_w, conv_b, gamma, beta,
                                           (float*)d_out, (unsigned*)d_ws);
}

// Round 3
// 73.599 us; speedup vs baseline: 1.1970x; 1.1970x over previous
//
#include <hip/hip_runtime.h>
#include <math.h>

namespace {
constexpr int kB = 2, kC = 3, kOC = 2, kH = 96, kW = 96;
constexpr int kN      = kH * kW;        // 9216
constexpr int kChunks = kN / 256;       // 36
constexpr float kEps   = 1e-5f;
constexpr float kScale = 0.57735026918962576f;  // 1/sqrt(3)
// ws float layout:
constexpr int WS_M = 0;     // 18 floats: M[b][cp][c]
constexpr int WS_P = 32;    // 72*4 floats: per-block (sum0, sq0, sum1, sq1)
constexpr int WS_Y = 512;   // 36864 floats: pre-BN y, [b*2+oc][pix]
}

// K1: M[b][cp][c] = sum_n Xhat[b,cp,n] * X[b,c,n]  (18 blocks, one dot each)
__global__ __launch_bounds__(256) void k1_gram(const float* __restrict__ X,
                                               const float* __restrict__ Xh,
                                               float* __restrict__ ws) {
    const int idx = blockIdx.x;              // 0..17
    const int b = idx / 9, cp = (idx % 9) / 3, c = idx % 3;
    const float4* kp = (const float4*)(Xh + (size_t)(b * kC + cp) * kN);
    const float4* qp = (const float4*)(X  + (size_t)(b * kC + c ) * kN);
    float part = 0.f;
    for (int n = threadIdx.x; n < kN / 4; n += 256) {   // 9 iters/thread
        const float4 a = kp[n], q = qp[n];
        part += a.x * q.x + a.y * q.y + a.z * q.z + a.w * q.w;
    }
    #pragma unroll
    for (int off = 32; off > 0; off >>= 1) part += __shfl_down(part, off);
    __shared__ float sw[4];
    if ((threadIdx.x & 63) == 0) sw[threadIdx.x >> 6] = part;
    __syncthreads();
    if (threadIdx.x == 0) ws[WS_M + idx] = sw[0] + sw[1] + sw[2] + sw[3];
}

// K2: y[oc,p] = cb[oc] + sum_nb sum_cp E[oc,cp,nb] * q[cp, p+nb]
//     E[oc,cp,nb] = kScale * sum_ic W[oc,ic,nb] * M[cp,ic]
// 72 blocks = (b, 256-pixel chunk); both oc per thread; per-block stat slots.
__global__ __launch_bounds__(256) void k2_conv(const float* __restrict__ X,
                                               const float* __restrict__ cw,
                                               const float* __restrict__ cb,
                                               float* __restrict__ ws) {
    const int tid = threadIdx.x;
    const int blk = blockIdx.x;              // 0..71
    const int b   = blk / kChunks;
    const int pix = (blk % kChunks) * 256 + tid;
    const int h = pix / kW, w = pix % kW;

    __shared__ float sM[9];
    __shared__ float sE[2][3][9];
    if (tid < 9) sM[tid] = ws[WS_M + b * 9 + tid];
    __syncthreads();
    if (tid < 54) {
        const int oc = tid / 27, r = tid % 27, cp = r / 9, nb = r % 9;
        sE[oc][cp][nb] = kScale * (cw[oc * 27 +      nb] * sM[cp * 3 + 0] +
                                   cw[oc * 27 +  9 + nb] * sM[cp * 3 + 1] +
                                   cw[oc * 27 + 18 + nb] * sM[cp * 3 + 2]);
    }
    __syncthreads();

    const float* qb = X + (size_t)b * kC * kN;
    float acc0 = cb[0], acc1 = cb[1];
    #pragma unroll
    for (int dh = 0; dh < 3; ++dh) {
        const int hh = h + dh - 1;
        if (hh < 0 || hh >= kH) continue;
        #pragma unroll
        for (int dw = 0; dw < 3; ++dw) {
            const int ww = w + dw - 1;
            if (ww < 0 || ww >= kW) continue;
            const int p = hh * kW + ww, nb = dh * 3 + dw;
            const float q0 = qb[p], q1 = qb[kN + p], q2 = qb[2 * kN + p];
            acc0 += q0 * sE[0][0][nb] + q1 * sE[0][1][nb] + q2 * sE[0][2][nb];
            acc1 += q0 * sE[1][0][nb] + q1 * sE[1][1][nb] + q2 * sE[1][2][nb];
        }
    }
    ws[WS_Y + (b * kOC + 0) * kN + pix] = acc0;
    ws[WS_Y + (b * kOC + 1) * kN + pix] = acc1;

    float v0 = acc0, v1 = acc0 * acc0, v2 = acc1, v3 = acc1 * acc1;
    #pragma unroll
    for (int off = 32; off > 0; off >>= 1) {
        v0 += __shfl_down(v0, off); v1 += __shfl_down(v1, off);
        v2 += __shfl_down(v2, off); v3 += __shfl_down(v3, off);
    }
    __shared__ float sP[4][4];
    if ((tid & 63) == 0) {
        const int wv = tid >> 6;
        sP[wv][0] = v0; sP[wv][1] = v1; sP[wv][2] = v2; sP[wv][3] = v3;
    }
    __syncthreads();
    if (tid < 4) ws[WS_P + blk * 4 + tid] = sP[0][tid] + sP[1][tid] + sP[2][tid] + sP[3][tid];
}

// K3: reduce 72 partials per channel, BN (biased var) + gamma/beta + LeakyReLU
__global__ __launch_bounds__(256) void k3_bn(const float* __restrict__ ws,
                                             const float* __restrict__ gamma,
                                             const float* __restrict__ beta,
                                             float* __restrict__ out) {
    const int tid = threadIdx.x;
    const int i   = blockIdx.x * 256 + tid;   // 0..36863
    const int oc  = (i / kN) & 1;             // uniform per block (kN % 256 == 0)
    __shared__ float sS[128], sQ[128];
    if (tid < 128) {
        float s = 0.f, q = 0.f;
        if (tid < 72) {
            s = ws[WS_P + tid * 4 + oc * 2];
            q = ws[WS_P + tid * 4 + oc * 2 + 1];
        }
        sS[tid] = s; sQ[tid] = q;
    }
    __syncthreads();
    for (int st = 64; st > 0; st >>= 1) {
        if (tid < st) { sS[tid] += sS[tid + st]; sQ[tid] += sQ[tid + st]; }
        __syncthreads();
    }
    const float inv  = 1.f / (float)(kB * kN);
    const float mean = sS[0] * inv;
    const float var  = sQ[0] * inv - mean * mean;
    const float g    = gamma[oc] * rsqrtf(var + kEps);
    const float bt   = beta[oc];
    const float y = (ws[WS_Y + i] - mean) * g + bt;
    out[i] = (y >= 0.f) ? y : 0.1f * y;
}

extern "C" void kernel_launch(void* const* d_in, const int* in_sizes, int n_in,
                              void* d_out, int out_size, void* d_ws, size_t ws_size,
                              hipStream_t stream) {
    const float* X      = (const float*)d_in[0];  // X_tnext     (2,3,96,96)
    const float* Xhat   = (const float*)d_in[1];  // X_hat_tnext (2,3,96,96)
    const float* conv_w = (const float*)d_in[2];  // (2,3,3,3)
    const float* conv_b = (const float*)d_in[3];  // (2,)
    const float* gamma  = (const float*)d_in[4];  // (2,)
    const float* beta   = (const float*)d_in[5];  // (2,)
    float* ws  = (float*)d_ws;

    k1_gram<<<kB * 9, 256, 0, stream>>>(X, Xhat, ws);
    k2_conv<<<kB * kChunks, 256, 0, stream>>>(X, conv_w, conv_b, ws);
    k3_bn  <<<kB * kOC * kChunks, 256, 0, stream>>>(ws, gamma, beta, (float*)d_out);
}

// Round 4
// 71.846 us; speedup vs baseline: 1.2262x; 1.0244x over previous
//
#include <hip/hip_runtime.h>
#include <math.h>

namespace {
constexpr int kB = 2, kC = 3, kOC = 2, kH = 96, kW = 96;
constexpr int kN      = kH * kW;        // 9216
constexpr int kChunks = kN / 256;       // 36
constexpr int kBlocks = kB * kChunks;   // 72
constexpr float kEps   = 1e-5f;
constexpr float kScale = 0.57735026918962576f;  // 1/sqrt(3)
// ws float layout:
constexpr int WS_P = 0;     // 72 float4: per-block (sum0, sq0, sum1, sq1)
constexpr int WS_Y = 512;   // 2*9216 float2: pre-BN y interleaved [b][pix][oc]
}

// kA: per-block Gram (redundant) -> E tensor -> conv for both oc -> y + stat partials
__global__ __launch_bounds__(256) void kA_conv(const float* __restrict__ X,
                                               const float* __restrict__ Xh,
                                               const float* __restrict__ cw,
                                               const float* __restrict__ cb,
                                               float* __restrict__ ws) {
    const int tid = threadIdx.x;
    const int blk = blockIdx.x;              // 0..71
    const int b   = blk / kChunks;
    const int pix = (blk % kChunks) * 256 + tid;
    const int h = pix / kW, w = pix % kW;

    // ---- Gram M[cp][c] = sum_n Xh[b,cp,n] * X[b,c,n]  (block-local, redundant)
    const float*  qb  = X  + (size_t)b * kC * kN;
    const float4* qb4 = (const float4*)qb;
    const float4* kb4 = (const float4*)(Xh + (size_t)b * kC * kN);
    float m[9] = {0,0,0,0,0,0,0,0,0};
    for (int n = tid; n < kN / 4; n += 256) {            // 9 iters
        const float4 q0 = qb4[n], q1 = qb4[kN/4 + n], q2 = qb4[2*kN/4 + n];
        const float4 k0 = kb4[n], k1 = kb4[kN/4 + n], k2 = kb4[2*kN/4 + n];
        m[0] += k0.x*q0.x + k0.y*q0.y + k0.z*q0.z + k0.w*q0.w;
        m[1] += k0.x*q1.x + k0.y*q1.y + k0.z*q1.z + k0.w*q1.w;
        m[2] += k0.x*q2.x + k0.y*q2.y + k0.z*q2.z + k0.w*q2.w;
        m[3] += k1.x*q0.x + k1.y*q0.y + k1.z*q0.z + k1.w*q0.w;
        m[4] += k1.x*q1.x + k1.y*q1.y + k1.z*q1.z + k1.w*q1.w;
        m[5] += k1.x*q2.x + k1.y*q2.y + k1.z*q2.z + k1.w*q2.w;
        m[6] += k2.x*q0.x + k2.y*q0.y + k2.z*q0.z + k2.w*q0.w;
        m[7] += k2.x*q1.x + k2.y*q1.y + k2.z*q1.z + k2.w*q1.w;
        m[8] += k2.x*q2.x + k2.y*q2.y + k2.z*q2.z + k2.w*q2.w;
    }
    #pragma unroll
    for (int off = 32; off > 0; off >>= 1) {
        #pragma unroll
        for (int j = 0; j < 9; ++j) m[j] += __shfl_down(m[j], off);
    }
    __shared__ float sMw[4][9];
    __shared__ float sM[9];
    __shared__ float sE[2][3][9];
    if ((tid & 63) == 0) {
        #pragma unroll
        for (int j = 0; j < 9; ++j) sMw[tid >> 6][j] = m[j];
    }
    __syncthreads();
    if (tid < 9) sM[tid] = sMw[0][tid] + sMw[1][tid] + sMw[2][tid] + sMw[3][tid];
    __syncthreads();
    // E[oc][cp][nb] = kScale * sum_ic W[oc,ic,nb] * M[cp,ic]
    if (tid < 54) {
        const int oc = tid / 27, r = tid % 27, cp = r / 9, nb = r % 9;
        sE[oc][cp][nb] = kScale * (cw[oc * 27 +      nb] * sM[cp * 3 + 0] +
                                   cw[oc * 27 +  9 + nb] * sM[cp * 3 + 1] +
                                   cw[oc * 27 + 18 + nb] * sM[cp * 3 + 2]);
    }
    __syncthreads();

    // ---- conv: y[oc,p] = cb[oc] + sum_nb sum_cp E[oc,cp,nb] * q[cp, p+nb]
    float acc0 = cb[0], acc1 = cb[1];
    #pragma unroll
    for (int dh = 0; dh < 3; ++dh) {
        const int hh = h + dh - 1;
        if (hh < 0 || hh >= kH) continue;
        #pragma unroll
        for (int dw = 0; dw < 3; ++dw) {
            const int ww = w + dw - 1;
            if (ww < 0 || ww >= kW) continue;
            const int p = hh * kW + ww, nb = dh * 3 + dw;
            const float q0 = qb[p], q1 = qb[kN + p], q2 = qb[2 * kN + p];
            acc0 += q0 * sE[0][0][nb] + q1 * sE[0][1][nb] + q2 * sE[0][2][nb];
            acc1 += q0 * sE[1][0][nb] + q1 * sE[1][1][nb] + q2 * sE[1][2][nb];
        }
    }
    ((float2*)(ws + WS_Y))[(size_t)b * kN + pix] = make_float2(acc0, acc1);

    // ---- per-block stat partials (sum, sumsq per oc)
    float v0 = acc0, v1 = acc0 * acc0, v2 = acc1, v3 = acc1 * acc1;
    #pragma unroll
    for (int off = 32; off > 0; off >>= 1) {
        v0 += __shfl_down(v0, off); v1 += __shfl_down(v1, off);
        v2 += __shfl_down(v2, off); v3 += __shfl_down(v3, off);
    }
    __shared__ float sP[4][4];
    if ((tid & 63) == 0) {
        const int wv = tid >> 6;
        sP[wv][0] = v0; sP[wv][1] = v1; sP[wv][2] = v2; sP[wv][3] = v3;
    }
    __syncthreads();
    if (tid < 4)
        ws[WS_P + blk * 4 + tid] = sP[0][tid] + sP[1][tid] + sP[2][tid] + sP[3][tid];
}

// kB: reduce 72 partial float4s, finalize BN (biased var) + gamma/beta + LeakyReLU
__global__ __launch_bounds__(256) void kB_bn(const float* __restrict__ ws,
                                             const float* __restrict__ gamma,
                                             const float* __restrict__ beta,
                                             float* __restrict__ out) {
    const int tid = threadIdx.x;
    const int blk = blockIdx.x;              // 0..71
    const int b   = blk / kChunks;
    const int pix = (blk % kChunks) * 256 + tid;

    __shared__ float4 sR[128];
    if (tid < 128) {
        float4 p = make_float4(0.f, 0.f, 0.f, 0.f);
        if (tid < kBlocks) p = ((const float4*)(ws + WS_P))[tid];
        sR[tid] = p;
    }
    __syncthreads();
    for (int s = 64; s > 0; s >>= 1) {
        if (tid < s) {
            float4 a = sR[tid], c = sR[tid + s];
            sR[tid] = make_float4(a.x + c.x, a.y + c.y, a.z + c.z, a.w + c.w);
        }
        __syncthreads();
    }
    const float4 tot = sR[0];
    const float inv   = 1.f / (float)(kB * kN);
    const float mean0 = tot.x * inv, mean1 = tot.z * inv;
    const float g0 = gamma[0] * rsqrtf(tot.y * inv - mean0 * mean0 + kEps);
    const float g1 = gamma[1] * rsqrtf(tot.w * inv - mean1 * mean1 + kEps);
    const float b0 = beta[0], b1 = beta[1];

    const float2 y2 = ((const float2*)(ws + WS_Y))[(size_t)b * kN + pix];
    float y0 = (y2.x - mean0) * g0 + b0;
    float y1 = (y2.y - mean1) * g1 + b1;
    out[(size_t)(b * kOC + 0) * kN + pix] = (y0 >= 0.f) ? y0 : 0.1f * y0;
    out[(size_t)(b * kOC + 1) * kN + pix] = (y1 >= 0.f) ? y1 : 0.1f * y1;
}

extern "C" void kernel_launch(void* const* d_in, const int* in_sizes, int n_in,
                              void* d_out, int out_size, void* d_ws, size_t ws_size,
                              hipStream_t stream) {
    const float* X      = (const float*)d_in[0];  // X_tnext     (2,3,96,96)
    const float* Xhat   = (const float*)d_in[1];  // X_hat_tnext (2,3,96,96)
    const float* conv_w = (const float*)d_in[2];  // (2,3,3,3)
    const float* conv_b = (const float*)d_in[3];  // (2,)
    const float* gamma  = (const float*)d_in[4];  // (2,)
    const float* beta   = (const float*)d_in[5];  // (2,)
    float* ws = (float*)d_ws;

    kA_conv<<<kBlocks, 256, 0, stream>>>(X, Xhat, conv_w, conv_b, ws);
    kB_bn  <<<kBlocks, 256, 0, stream>>>(ws, gamma, beta, (float*)d_out);
}